// Round 3
// baseline (63.979 us; speedup 1.0000x reference)
//
#include <hip/hip_runtime.h>
#include <cstdint>

#define BB 8
#define NN 2048
#define CC 64
#define TI 64            // i-rows per block in k2 (4 waves x 16)
#define JSPLIT 4
#define KRANGE (NN / JSPLIT)   // 512
#define JCH 128                // j-chunk staged in LDS

typedef __attribute__((ext_vector_type(8))) __bf16 bf16x8;
typedef __attribute__((ext_vector_type(4))) float f32x4;
typedef __attribute__((ext_vector_type(4))) unsigned int u32x4;

// ws layout (in floats):
static const size_t WS_H   = 0;                                  // B*N*C
static const size_t WS_E1  = WS_H  + (size_t)BB*NN*CC;           // B*N
static const size_t WS_E2  = WS_E1 + (size_t)BB*NN;              // B*N
static const size_t WS_HT  = WS_E2 + (size_t)BB*NN;              // hiT+loT bf16: 2*B*C*N ushorts = B*C*N floats
static const size_t WS_ACC = WS_HT + (size_t)BB*CC*NN;           // JSPLIT*B*N*C floats
static const size_t WS_Z   = WS_ACC + (size_t)JSPLIT*BB*NN*CC;   // JSPLIT*B*N

// ---------------- Kernel 1: h = inp @ W ; e1 = h@a1 ; e2 = h@a2 ----------------
__global__ __launch_bounds__(256) void k1_proj(const float* __restrict__ inp,
        const float* __restrict__ Wm, const float* __restrict__ av,
        float* __restrict__ h, float* __restrict__ e1, float* __restrict__ e2) {
    __shared__ float inp_lds[256];
    int t = threadIdx.x;
    size_t base = (size_t)blockIdx.x * 256;
    inp_lds[t] = inp[base + t];
    __syncthreads();
    int r = t >> 6;
    int c = t & 63;
    const float* irow = &inp_lds[r * 64];
    float acc = 0.f;
    #pragma unroll
    for (int k = 0; k < 64; k++) acc = fmaf(irow[k], Wm[k * 64 + c], acc);
    size_t row = (size_t)blockIdx.x * 4 + r;
    h[row * 64 + c] = acc;
    float v1 = acc * av[c];
    float v2 = acc * av[64 + c];
    #pragma unroll
    for (int o = 32; o > 0; o >>= 1) {
        v1 += __shfl_down(v1, o);
        v2 += __shfl_down(v2, o);
    }
    if (c == 0) { e1[row] = v1; e2[row] = v2; }
}

// ---------------- Kernel 1b: transpose h -> bf16 hi/lo, layout [b][c][n] ----------------
__global__ __launch_bounds__(256) void k1b_transpose(const float* __restrict__ h,
        unsigned short* __restrict__ hiT, unsigned short* __restrict__ loT) {
    __shared__ float tile[64][65];
    int t = threadIdx.x;
    int b = blockIdx.x >> 5;           // N/64 = 32 tiles
    int i0 = (blockIdx.x & 31) * 64;
    const float* hb = h + ((size_t)b * NN + i0) * CC;
    #pragma unroll
    for (int q = 0; q < 16; q++) {
        int idx = q * 256 + t;
        tile[idx >> 6][idx & 63] = hb[idx];
    }
    __syncthreads();
    int c = t & 63;
    int rgrp = t >> 6;           // 4 groups of 16 rows
    unsigned int uh[8], ul[8];
    #pragma unroll
    for (int p = 0; p < 8; p++) {
        unsigned int pack_h = 0, pack_l = 0;
        #pragma unroll
        for (int s = 0; s < 2; s++) {
            float v = tile[rgrp * 16 + p * 2 + s][c];
            __bf16 bh = (__bf16)v;
            float fh = (float)bh;
            __bf16 bl = (__bf16)(v - fh);
            unsigned int ubh = (unsigned int)__builtin_bit_cast(unsigned short, bh);
            unsigned int ubl = (unsigned int)__builtin_bit_cast(unsigned short, bl);
            pack_h |= ubh << (16 * s);
            pack_l |= ubl << (16 * s);
        }
        uh[p] = pack_h; ul[p] = pack_l;
    }
    size_t off = ((size_t)b * 64 + c) * NN + i0 + rgrp * 16;   // in ushorts
    u32x4* dh = (u32x4*)(hiT + off);
    u32x4* dl = (u32x4*)(loT + off);
    dh[0] = u32x4{uh[0], uh[1], uh[2], uh[3]};
    dh[1] = u32x4{uh[4], uh[5], uh[6], uh[7]};
    dl[0] = u32x4{ul[0], ul[1], ul[2], ul[3]};
    dl[1] = u32x4{ul[4], ul[5], ul[6], ul[7]};
}

// ---------------- Kernel 2: MFMA attention ----------------
// grid: b * 32tiles * JSPLIT. block 256 = 4 waves, wave w owns rows i0+w*16..+15.
// A-frag (p): lane l -> row (l&15), j-slots (l>>4)*8..+7 of each K=32 step.
// B-frag (h): staged transposed in LDS, swizzled, read as ds_read_b128.
__global__ __launch_bounds__(256) void k2_mfma(const int* __restrict__ adj,
        const unsigned short* __restrict__ hiT, const unsigned short* __restrict__ loT,
        const float* __restrict__ e1, const float* __restrict__ e2,
        float* __restrict__ accp, float* __restrict__ zp) {
    __shared__ __align__(16) char smem[2 * 16384 + 512];
    char* hiL = smem;                   // 64 rows x 256B (128 bf16), swizzled
    char* loL = smem + 16384;
    float* e2c = (float*)(smem + 32768);  // 128 floats

    int bid = blockIdx.x;
    int s    = bid & (JSPLIT - 1);
    int tile = (bid / JSPLIT) & 31;
    int b    = bid / (JSPLIT * 32);
    int i0 = tile * TI;
    int jbase = s * KRANGE;

    int t = threadIdx.x;
    int w = t >> 6;
    int l = t & 63;
    int col = l & 15;
    int kg  = l >> 4;       // k-group 0..3

    const int* adjrow = adj + ((size_t)b * NN + i0 + w * 16 + col) * NN;
    float e1v = e1[(size_t)b * NN + i0 + w * 16 + col];
    const float* e2b = e2 + (size_t)b * NN;
    const unsigned short* hiTb = hiT + (size_t)b * 64 * NN;
    const unsigned short* loTb = loT + (size_t)b * 64 * NN;

    f32x4 acc[4];
    #pragma unroll
    for (int n = 0; n < 4; n++) acc[n] = f32x4{0.f, 0.f, 0.f, 0.f};
    f32x4 accZ = f32x4{0.f, 0.f, 0.f, 0.f};

    __bf16 onev = (__bf16)1.0f, zerov = (__bf16)0.0f;
    bf16x8 onesf;
    #pragma unroll
    for (int i = 0; i < 8; i++) onesf[i] = (col == 0) ? onev : zerov;

    for (int jc = 0; jc < KRANGE / JCH; jc++) {
        int j0 = jbase + jc * JCH;
        // ---- prefetch this chunk's adj (8 x int4) so latency hides under staging ----
        int4 a8[8];
        #pragma unroll
        for (int ks = 0; ks < 4; ks++) {
            const int4* ap = (const int4*)(adjrow + j0 + ks * 32 + kg * 8);
            a8[2 * ks]     = ap[0];
            a8[2 * ks + 1] = ap[1];
        }
        // ---- stage hiT/loT chunk (swizzled) + e2 chunk ----
        #pragma unroll
        for (int q = 0; q < 8; q++) {
            int g = q * 256 + t;           // 2048 16B-granules
            int buf = g >> 10;
            int rem = g & 1023;
            int c = rem >> 4;
            int seg = rem & 15;
            f32x4 v = *(const f32x4*)((buf ? loTb : hiTb) + ((size_t)c * NN + j0 + seg * 8));
            *(f32x4*)((buf ? loL : hiL) + c * 256 + ((seg ^ (c & 7)) << 4)) = v;
        }
        if (t < 32) {
            ((f32x4*)e2c)[t] = *(const f32x4*)(e2b + j0 + t * 4);
        }
        __syncthreads();

        // ---- 4 K-steps of 32 ----
        #pragma unroll
        for (int ks = 0; ks < 4; ks++) {
            int krel = ks * 32 + kg * 8;
            int4 a0 = a8[2 * ks];
            int4 a1 = a8[2 * ks + 1];
            f32x4 e20 = *(f32x4*)(e2c + krel);
            f32x4 e21 = *(f32x4*)(e2c + krel + 4);
            float xs[8] = {e20.x, e20.y, e20.z, e20.w, e21.x, e21.y, e21.z, e21.w};
            int ms[8] = {a0.x, a0.y, a0.z, a0.w, a1.x, a1.y, a1.z, a1.w};
            bf16x8 pf;
            #pragma unroll
            for (int i = 0; i < 8; i++) {
                float x = e1v + xs[i];
                x = fmaxf(x, 0.01f * x);
                x = __expf(x);
                x = (ms[i] > 0) ? x : 0.0f;
                pf[i] = (__bf16)x;
            }
            int seg = ks * 4 + kg;
            #pragma unroll
            for (int n = 0; n < 4; n++) {
                int c = n * 16 + col;
                int boff = c * 256 + ((seg ^ (c & 7)) << 4);
                bf16x8 bhi = __builtin_bit_cast(bf16x8, *(f32x4*)(hiL + boff));
                bf16x8 blo = __builtin_bit_cast(bf16x8, *(f32x4*)(loL + boff));
                acc[n] = __builtin_amdgcn_mfma_f32_16x16x32_bf16(pf, bhi, acc[n], 0, 0, 0);
                acc[n] = __builtin_amdgcn_mfma_f32_16x16x32_bf16(pf, blo, acc[n], 0, 0, 0);
            }
            accZ = __builtin_amdgcn_mfma_f32_16x16x32_bf16(pf, onesf, accZ, 0, 0, 0);
        }
        __syncthreads();
    }

    // ---- epilogue: C/D layout col = lane&15, row = (lane>>4)*4 + reg ----
    size_t orow = (size_t)s * BB * NN + (size_t)b * NN + i0 + w * 16 + kg * 4;
    float* accout = accp + orow * CC;
    #pragma unroll
    for (int n = 0; n < 4; n++) {
        #pragma unroll
        for (int r = 0; r < 4; r++) {
            accout[(size_t)r * CC + n * 16 + col] = acc[n][r];
        }
    }
    if (col == 0) {
        #pragma unroll
        for (int r = 0; r < 4; r++) zp[orow + r] = accZ[r];
    }
}

// ---------------- Kernel 3: out = sum_s acc[s] / sum_s z[s] ----------------
__global__ __launch_bounds__(256) void k3_final(const float* __restrict__ accp,
        const float* __restrict__ zp, float* __restrict__ out) {
    int idx = blockIdx.x * 256 + threadIdx.x;      // float4 index
    const int TOT4 = BB * NN * CC / 4;             // 262144
    if (idx >= TOT4) return;
    int row = idx >> 4;
    f32x4 s0 = ((const f32x4*)accp)[idx];
    f32x4 s1 = ((const f32x4*)accp)[idx + TOT4];
    f32x4 s2 = ((const f32x4*)accp)[idx + 2 * TOT4];
    f32x4 s3 = ((const f32x4*)accp)[idx + 3 * TOT4];
    float z = zp[row] + zp[row + BB * NN] + zp[row + 2 * BB * NN] + zp[row + 3 * BB * NN];
    float inv = (z > 0.f) ? (1.0f / z) : 0.f;
    f32x4 o;
    o.x = (s0.x + s1.x + s2.x + s3.x) * inv;
    o.y = (s0.y + s1.y + s2.y + s3.y) * inv;
    o.z = (s0.z + s1.z + s2.z + s3.z) * inv;
    o.w = (s0.w + s1.w + s2.w + s3.w) * inv;
    ((f32x4*)out)[idx] = o;
}

extern "C" void kernel_launch(void* const* d_in, const int* in_sizes, int n_in,
                              void* d_out, int out_size, void* d_ws, size_t ws_size,
                              hipStream_t stream) {
    const float* inp = (const float*)d_in[0];
    const int*   adj = (const int*)d_in[1];
    const float* Wm  = (const float*)d_in[2];
    const float* av  = (const float*)d_in[3];
    float* ws = (float*)d_ws;
    float* h    = ws + WS_H;
    float* e1   = ws + WS_E1;
    float* e2   = ws + WS_E2;
    unsigned short* hiT = (unsigned short*)(ws + WS_HT);
    unsigned short* loT = hiT + (size_t)BB * CC * NN;
    float* accp = ws + WS_ACC;
    float* zp   = ws + WS_Z;
    float* out  = (float*)d_out;

    k1_proj<<<BB * NN / 4, 256, 0, stream>>>(inp, Wm, av, h, e1, e2);
    k1b_transpose<<<BB * (NN / 64), 256, 0, stream>>>(h, hiT, loT);
    k2_mfma<<<BB * 32 * JSPLIT, 256, 0, stream>>>(adj, hiT, loT, e1, e2, accp, zp);
    k3_final<<<(BB * NN * CC / 4 + 255) / 256, 256, 0, stream>>>(accp, zp, out);
}

// Round 4
// 56.781 us; speedup vs baseline: 1.1268x; 1.1268x over previous
//
#include <hip/hip_runtime.h>
#include <cstdint>

#define BB 8
#define NN 2048
#define CC 64
#define TI 64            // i-rows per block in k2 (4 waves x 16)
#define JSPLIT 2
#define KRANGE (NN / JSPLIT)   // 1024
#define JCH 128                // j-chunk staged in LDS
#define NCH (KRANGE / JCH)     // 8 chunks

typedef __attribute__((ext_vector_type(8))) __bf16 bf16x8;
typedef __attribute__((ext_vector_type(4))) float f32x4;
typedef __attribute__((ext_vector_type(4))) unsigned int u32x4;

// ws layout (in floats):
static const size_t WS_H   = 0;                                  // B*N*C
static const size_t WS_E1  = WS_H  + (size_t)BB*NN*CC;           // B*N
static const size_t WS_E2  = WS_E1 + (size_t)BB*NN;              // B*N
static const size_t WS_HT  = WS_E2 + (size_t)BB*NN;              // hiT+loT bf16
static const size_t WS_ACC = WS_HT + (size_t)BB*CC*NN;           // JSPLIT*B*N*C floats
static const size_t WS_Z   = WS_ACC + (size_t)JSPLIT*BB*NN*CC;   // JSPLIT*B*N

// async global->LDS, 16B and 4B widths; LDS dest = wave-uniform base + lane*width
#define GL16(g, l) __builtin_amdgcn_global_load_lds( \
    (const __attribute__((address_space(1))) void*)(g), \
    (__attribute__((address_space(3))) void*)(uint32_t)(uintptr_t)(l), 16, 0, 0)
#define GL4(g, l) __builtin_amdgcn_global_load_lds( \
    (const __attribute__((address_space(1))) void*)(g), \
    (__attribute__((address_space(3))) void*)(uint32_t)(uintptr_t)(l), 4, 0, 0)
#define WAIT18() asm volatile("s_waitcnt vmcnt(18)" ::: "memory")
#define WAIT0()  asm volatile("s_waitcnt vmcnt(0)" ::: "memory")
#define BAR()    __builtin_amdgcn_s_barrier()

// ---------------- Kernel 1: h = inp @ W ; e1 = h@a1 ; e2 = h@a2 ----------------
__global__ __launch_bounds__(256) void k1_proj(const float* __restrict__ inp,
        const float* __restrict__ Wm, const float* __restrict__ av,
        float* __restrict__ h, float* __restrict__ e1, float* __restrict__ e2) {
    __shared__ float inp_lds[256];
    int t = threadIdx.x;
    size_t base = (size_t)blockIdx.x * 256;
    inp_lds[t] = inp[base + t];
    __syncthreads();
    int r = t >> 6;
    int c = t & 63;
    const float* irow = &inp_lds[r * 64];
    float acc = 0.f;
    #pragma unroll
    for (int k = 0; k < 64; k++) acc = fmaf(irow[k], Wm[k * 64 + c], acc);
    size_t row = (size_t)blockIdx.x * 4 + r;
    h[row * 64 + c] = acc;
    float v1 = acc * av[c];
    float v2 = acc * av[64 + c];
    #pragma unroll
    for (int o = 32; o > 0; o >>= 1) {
        v1 += __shfl_down(v1, o);
        v2 += __shfl_down(v2, o);
    }
    if (c == 0) { e1[row] = v1; e2[row] = v2; }
}

// ---------------- Kernel 1b: transpose h -> bf16 hi/lo, layout [b][c][n] ----------------
__global__ __launch_bounds__(256) void k1b_transpose(const float* __restrict__ h,
        unsigned short* __restrict__ hiT, unsigned short* __restrict__ loT) {
    __shared__ float tile[64][65];
    int t = threadIdx.x;
    int b = blockIdx.x >> 5;           // N/64 = 32 tiles
    int i0 = (blockIdx.x & 31) * 64;
    const float* hb = h + ((size_t)b * NN + i0) * CC;
    #pragma unroll
    for (int q = 0; q < 16; q++) {
        int idx = q * 256 + t;
        tile[idx >> 6][idx & 63] = hb[idx];
    }
    __syncthreads();
    int c = t & 63;
    int rgrp = t >> 6;           // 4 groups of 16 rows
    unsigned int uh[8], ul[8];
    #pragma unroll
    for (int p = 0; p < 8; p++) {
        unsigned int pack_h = 0, pack_l = 0;
        #pragma unroll
        for (int s = 0; s < 2; s++) {
            float v = tile[rgrp * 16 + p * 2 + s][c];
            __bf16 bh = (__bf16)v;
            float fh = (float)bh;
            __bf16 bl = (__bf16)(v - fh);
            unsigned int ubh = (unsigned int)__builtin_bit_cast(unsigned short, bh);
            unsigned int ubl = (unsigned int)__builtin_bit_cast(unsigned short, bl);
            pack_h |= ubh << (16 * s);
            pack_l |= ubl << (16 * s);
        }
        uh[p] = pack_h; ul[p] = pack_l;
    }
    size_t off = ((size_t)b * 64 + c) * NN + i0 + rgrp * 16;   // in ushorts
    u32x4* dh = (u32x4*)(hiT + off);
    u32x4* dl = (u32x4*)(loT + off);
    dh[0] = u32x4{uh[0], uh[1], uh[2], uh[3]};
    dh[1] = u32x4{uh[4], uh[5], uh[6], uh[7]};
    dl[0] = u32x4{ul[0], ul[1], ul[2], ul[3]};
    dl[1] = u32x4{ul[4], ul[5], ul[6], ul[7]};
}

// ---------------- Kernel 2: MFMA attention, async double-buffered pipeline ----------------
// grid: b(8) x tile(32) x s(2). block 256 = 4 waves, wave w owns rows i0+w*16..+15.
__global__ __launch_bounds__(256) void k2_mfma(const int* __restrict__ adj,
        const unsigned short* __restrict__ hiT, const unsigned short* __restrict__ loT,
        const float* __restrict__ e1, const float* __restrict__ e2,
        float* __restrict__ accp, float* __restrict__ zp) {
    __shared__ __align__(16) char smem[2 * 32768 + 2 * 512];
    char* hi0 = smem;              // each 16 KB: 64 rows x 256B (128 bf16), swizzled
    char* lo0 = smem + 16384;
    char* hi1 = smem + 32768;
    char* lo1 = smem + 49152;
    char* e2L0 = smem + 65536;     // 512 B each
    char* e2L1 = smem + 66048;

    int bid = blockIdx.x;
    int s    = bid & (JSPLIT - 1);
    int tile = (bid >> 1) & 31;
    int b    = bid >> 6;
    int i0 = tile * TI;
    int jbase = s * KRANGE;

    int t = threadIdx.x;
    int w = t >> 6;
    int l = t & 63;
    int col = l & 15;
    int kg  = l >> 4;       // k-group 0..3

    // staging geometry: wave w covers granules [w*512, w*512+512) of 2048
    int wlo = (w >> 1);               // waves 2,3 stage loT
    int cw  = (w & 1) * 32;           // base channel row
    int l4  = l >> 4;
    int sl  = l & 15;
    int wq_off = (w & 1) * 8192;      // byte offset within the 16KB half

    const int* adjrow = adj + ((size_t)b * NN + i0 + w * 16 + col) * NN;
    float e1v = e1[(size_t)b * NN + i0 + w * 16 + col];
    const float* e2b = e2 + (size_t)b * NN;
    const unsigned short* hiTb = hiT + (size_t)b * 64 * NN;
    const unsigned short* loTb = loT + (size_t)b * 64 * NN;
    const unsigned short* sTb = wlo ? loTb : hiTb;

    f32x4 acc[4];
    #pragma unroll
    for (int n = 0; n < 4; n++) acc[n] = f32x4{0.f, 0.f, 0.f, 0.f};
    f32x4 accZ = f32x4{0.f, 0.f, 0.f, 0.f};

    __bf16 onev = (__bf16)1.0f, zerov = (__bf16)0.0f;
    bf16x8 onesf;
    #pragma unroll
    for (int i = 0; i < 8; i++) onesf[i] = (col == 0) ? onev : zerov;

    int4 aA[8], aB[8];

#define STAGE(jcN, B) { \
    int j0s = jbase + (jcN) * JCH; \
    char* lb = (wlo ? ((B) ? lo1 : lo0) : ((B) ? hi1 : hi0)) + wq_off; \
    _Pragma("unroll") \
    for (int q = 0; q < 8; q++) { \
        int c = cw + q * 4 + l4; \
        const unsigned short* src = sTb + (size_t)c * NN + j0s + ((sl ^ (c & 7)) << 3); \
        GL16(src, lb + q * 1024); \
    } \
    GL4(e2b + j0s + l, ((B) ? e2L1 : e2L0)); \
    GL4(e2b + j0s + 64 + l, ((B) ? e2L1 : e2L0) + 256); \
}

#define ADJP(jcN, arr) { \
    int j0a = jbase + (jcN) * JCH; \
    _Pragma("unroll") \
    for (int ks = 0; ks < 4; ks++) { \
        const int4* ap = (const int4*)(adjrow + j0a + ks * 32 + kg * 8); \
        arr[2 * ks]     = ap[0]; \
        arr[2 * ks + 1] = ap[1]; \
    } \
}

#define COMPUTE(B, arr) { \
    const char* hiLb = (B) ? hi1 : hi0; \
    const char* loLb = (B) ? lo1 : lo0; \
    const float* e2c = (const float*)((B) ? e2L1 : e2L0); \
    _Pragma("unroll") \
    for (int ks = 0; ks < 4; ks++) { \
        int krel = ks * 32 + kg * 8; \
        int4 a0 = arr[2 * ks]; \
        int4 a1 = arr[2 * ks + 1]; \
        f32x4 e20 = *(const f32x4*)(e2c + krel); \
        f32x4 e21 = *(const f32x4*)(e2c + krel + 4); \
        float xs[8] = {e20.x, e20.y, e20.z, e20.w, e21.x, e21.y, e21.z, e21.w}; \
        int ms[8] = {a0.x, a0.y, a0.z, a0.w, a1.x, a1.y, a1.z, a1.w}; \
        bf16x8 pf; \
        _Pragma("unroll") \
        for (int i = 0; i < 8; i++) { \
            float x = e1v + xs[i]; \
            x = fmaxf(x, 0.01f * x); \
            x = __expf(x); \
            x = (ms[i] > 0) ? x : 0.0f; \
            pf[i] = (__bf16)x; \
        } \
        int seg = ks * 4 + kg; \
        _Pragma("unroll") \
        for (int n = 0; n < 4; n++) { \
            int c = n * 16 + col; \
            int boff = c * 256 + ((seg ^ (c & 7)) << 4); \
            bf16x8 bhi = __builtin_bit_cast(bf16x8, *(const f32x4*)(hiLb + boff)); \
            bf16x8 blo = __builtin_bit_cast(bf16x8, *(const f32x4*)(loLb + boff)); \
            acc[n] = __builtin_amdgcn_mfma_f32_16x16x32_bf16(pf, bhi, acc[n], 0, 0, 0); \
            acc[n] = __builtin_amdgcn_mfma_f32_16x16x32_bf16(pf, blo, acc[n], 0, 0, 0); \
        } \
        accZ = __builtin_amdgcn_mfma_f32_16x16x32_bf16(pf, onesf, accZ, 0, 0, 0); \
    } \
}

    // prologue: chunk 0 in flight
    STAGE(0, 0);
    ADJP(0, aA);

    #pragma unroll
    for (int jc = 0; jc < NCH; jc += 2) {
        // phase A: prefetch jc+1 into buf1/aB, compute jc from buf0/aA
        STAGE(jc + 1, 1);
        ADJP(jc + 1, aB);
        WAIT18();
        BAR();
        COMPUTE(0, aA);
        BAR();
        // phase B: prefetch jc+2 into buf0/aA, compute jc+1 from buf1/aB
        if (jc + 2 < NCH) {
            STAGE(jc + 2, 0);
            ADJP(jc + 2, aA);
            WAIT18();
        } else {
            WAIT0();
        }
        BAR();
        COMPUTE(1, aB);
        BAR();
    }

    // ---- epilogue: C/D layout col = lane&15, row = (lane>>4)*4 + reg ----
    size_t orow = (size_t)s * BB * NN + (size_t)b * NN + i0 + w * 16 + kg * 4;
    float* accout = accp + orow * CC;
    #pragma unroll
    for (int n = 0; n < 4; n++) {
        #pragma unroll
        for (int r = 0; r < 4; r++) {
            accout[(size_t)r * CC + n * 16 + col] = acc[n][r];
        }
    }
    if (col == 0) {
        #pragma unroll
        for (int r = 0; r < 4; r++) zp[orow + r] = accZ[r];
    }
#undef STAGE
#undef ADJP
#undef COMPUTE
}

// ---------------- Kernel 3: out = sum_s acc[s] / sum_s z[s] ----------------
__global__ __launch_bounds__(256) void k3_final(const float* __restrict__ accp,
        const float* __restrict__ zp, float* __restrict__ out) {
    int idx = blockIdx.x * 256 + threadIdx.x;      // float4 index
    const int TOT4 = BB * NN * CC / 4;             // 262144
    if (idx >= TOT4) return;
    int row = idx >> 4;
    f32x4 s0 = ((const f32x4*)accp)[idx];
    f32x4 s1 = ((const f32x4*)accp)[idx + TOT4];
    float z = zp[row] + zp[row + BB * NN];
    float inv = (z > 0.f) ? (1.0f / z) : 0.f;
    f32x4 o;
    o.x = (s0.x + s1.x) * inv;
    o.y = (s0.y + s1.y) * inv;
    o.z = (s0.z + s1.z) * inv;
    o.w = (s0.w + s1.w) * inv;
    ((f32x4*)out)[idx] = o;
}

extern "C" void kernel_launch(void* const* d_in, const int* in_sizes, int n_in,
                              void* d_out, int out_size, void* d_ws, size_t ws_size,
                              hipStream_t stream) {
    const float* inp = (const float*)d_in[0];
    const int*   adj = (const int*)d_in[1];
    const float* Wm  = (const float*)d_in[2];
    const float* av  = (const float*)d_in[3];
    float* ws = (float*)d_ws;
    float* h    = ws + WS_H;
    float* e1   = ws + WS_E1;
    float* e2   = ws + WS_E2;
    unsigned short* hiT = (unsigned short*)(ws + WS_HT);
    unsigned short* loT = hiT + (size_t)BB * CC * NN;
    float* accp = ws + WS_ACC;
    float* zp   = ws + WS_Z;
    float* out  = (float*)d_out;

    k1_proj<<<BB * NN / 4, 256, 0, stream>>>(inp, Wm, av, h, e1, e2);
    k1b_transpose<<<BB * (NN / 64), 256, 0, stream>>>(h, hiT, loT);
    k2_mfma<<<BB * 32 * JSPLIT, 256, 0, stream>>>(adj, hiT, loT, e1, e2, accp, zp);
    k3_final<<<(BB * NN * CC / 4 + 255) / 256, 256, 0, stream>>>(accp, zp, out);
}